// Round 1
// baseline (447.026 us; speedup 1.0000x reference)
//
#include <hip/hip_runtime.h>
#include <math.h>

#define Bn 64
#define Cn 64
#define Nn 325
#define Tn 12
#define ROWS (Bn * Tn * Nn)   // 249600 rows of the output softmax

// softplus matching jax.nn.softplus = logaddexp(x, 0) = max(x,0) + log1p(exp(-|x|))
__device__ __forceinline__ float sp(float x) {
    return fmaxf(x, 0.0f) + log1pf(expf(-fabsf(x)));
}

// Kernel 1: pooled means over channel halves -> softplus+1 -> pow(l1/l2).
// Thread mapping: tid = b*(N*T) + n*T + t  (t fastest) so that for each c the
// 64 lanes of a wave read consecutive addresses (perfect coalescing on x).
__global__ __launch_bounds__(256)
void pool_pow_kernel(const float* __restrict__ x,
                     const float* __restrict__ l1p, const float* __restrict__ l2p,
                     float* __restrict__ x1p, float* __restrict__ x2p) {
    int tid = blockIdx.x * blockDim.x + threadIdx.x;
    if (tid >= ROWS) return;
    int b = tid / (Nn * Tn);
    int r = tid - b * (Nn * Tn);   // r = n*Tn + t
    int n = r / Tn;
    int t = r - n * Tn;

    const float* p = x + (size_t)b * Cn * Nn * Tn + r;  // + c*(Nn*Tn) per channel
    float s1 = 0.0f, s2 = 0.0f;
#pragma unroll
    for (int c = 0; c < 32; ++c) s1 += p[c * (Nn * Tn)];
#pragma unroll
    for (int c = 32; c < 64; ++c) s2 += p[c * (Nn * Tn)];

    float v1 = sp(s1 * (1.0f / 32.0f)) + 1.0f;
    float v2 = sp(s2 * (1.0f / 32.0f)) + 1.0f;
    float l1 = sp(l1p[0]);
    float l2 = sp(l2p[0]);

    int o = (b * Tn + t) * Nn + n;   // [bt, n] layout
    x1p[o] = powf(v1, l1);
    x2p[o] = powf(v2, l2);
}

// Kernel 2: dist2 = dist^(2*l3)
__global__ __launch_bounds__(256)
void dist_pow_kernel(const float* __restrict__ dist, const float* __restrict__ l3p,
                     float* __restrict__ dist2) {
    int tid = blockIdx.x * blockDim.x + threadIdx.x;
    if (tid >= Nn * Nn) return;
    float e = 2.0f * sp(l3p[0]);
    dist2[tid] = powf(dist[tid], e);
}

// Kernel 3: one wave (64 lanes) per output row; 325 elements -> 6 regs/lane.
// a_ij = (g * (x1p_i * x2p_j)) * dist2_ij   (association matches reference)
__global__ __launch_bounds__(256)
void softmax_kernel(const float* __restrict__ x1p,
                    const float* __restrict__ x2p,
                    const float* __restrict__ dist2,
                    const float* __restrict__ Gp,
                    float* __restrict__ out) {
    int wid  = blockIdx.x * (blockDim.x >> 6) + (threadIdx.x >> 6);
    int lane = threadIdx.x & 63;
    if (wid >= ROWS) return;

    int bt = wid / Nn;
    int i  = wid - bt * Nn;

    float g   = sp(Gp[0]);
    float x1v = x1p[wid];                 // wid == bt*Nn + i
    const float* x2row = x2p + bt * Nn;   // reused across i -> L2
    const float* drow  = dist2 + i * Nn;  // reused across bt -> L2

    float a[6];
    float m = -INFINITY;
#pragma unroll
    for (int k = 0; k < 6; ++k) {
        int j = lane + 64 * k;
        float av = -INFINITY;
        if (j < Nn) av = (g * (x1v * x2row[j])) * drow[j];
        a[k] = av;
        m = fmaxf(m, av);
    }
#pragma unroll
    for (int off = 32; off; off >>= 1) m = fmaxf(m, __shfl_xor(m, off, 64));

    float s = 0.0f;
#pragma unroll
    for (int k = 0; k < 6; ++k) {
        int j = lane + 64 * k;
        float e = 0.0f;
        if (j < Nn) e = expf(a[k] - m);
        a[k] = e;
        s += e;
    }
#pragma unroll
    for (int off = 32; off; off >>= 1) s += __shfl_xor(s, off, 64);

    float inv = 1.0f / s;
    float* orow = out + (size_t)wid * Nn;
#pragma unroll
    for (int k = 0; k < 6; ++k) {
        int j = lane + 64 * k;
        if (j < Nn) orow[j] = a[k] * inv;
    }
}

extern "C" void kernel_launch(void* const* d_in, const int* in_sizes, int n_in,
                              void* d_out, int out_size, void* d_ws, size_t ws_size,
                              hipStream_t stream) {
    const float* x    = (const float*)d_in[0];
    const float* dist = (const float*)d_in[1];
    const float* l1   = (const float*)d_in[2];
    const float* l2   = (const float*)d_in[3];
    const float* l3   = (const float*)d_in[4];
    const float* G    = (const float*)d_in[5];
    float* out = (float*)d_out;

    float* ws    = (float*)d_ws;
    float* x1p   = ws;                 // ROWS floats
    float* x2p   = ws + ROWS;          // ROWS floats
    float* dist2 = ws + 2 * ROWS;      // Nn*Nn floats  (total ~2.4 MB)

    pool_pow_kernel<<<(ROWS + 255) / 256, 256, 0, stream>>>(x, l1, l2, x1p, x2p);
    dist_pow_kernel<<<(Nn * Nn + 255) / 256, 256, 0, stream>>>(dist, l3, dist2);
    softmax_kernel<<<ROWS / 4, 256, 0, stream>>>(x1p, x2p, dist2, G, out);
}

// Round 2
// 411.418 us; speedup vs baseline: 1.0865x; 1.0865x over previous
//
#include <hip/hip_runtime.h>
#include <math.h>

#define Bn 64
#define Cn 64
#define Nn 325
#define Tn 12
#define NT (Nn * Tn)           // 3900
#define ROWS (Bn * Tn * Nn)    // 249600 rows of the output softmax
#define QUADS (ROWS / 4)       // 62400 pool quads (4 rows each)
#define POOL_BLOCKS ((QUADS + 255) / 256)        // 244
#define DIST_BLOCKS ((Nn * Nn + 255) / 256)      // 413

// softplus matching jax.nn.softplus = max(x,0) + log1p(exp(-|x|))
__device__ __forceinline__ float sp(float x) {
    return fmaxf(x, 0.0f) + log1pf(expf(-fabsf(x)));
}

// Fused prep: blocks [0, POOL_BLOCKS) do pooled-mean -> softplus+1 -> pow;
// blocks [POOL_BLOCKS, +DIST_BLOCKS) do dist2 = dist^(2*l3).
// Pool mapping: quad q covers tids [4q, 4q+4), tid = b*NT + n*Tn + t (t fastest).
// NT % 4 == 0 and Tn % 4 == 0 so a quad never crosses b; float4 loads are
// 16B-aligned (b*Cn*NT, c*NT, r0 all multiples of 4 floats).
__global__ __launch_bounds__(256)
void prep_kernel(const float* __restrict__ x, const float* __restrict__ dist,
                 const float* __restrict__ l1p, const float* __restrict__ l2p,
                 const float* __restrict__ l3p,
                 float* __restrict__ x1p, float* __restrict__ x2p,
                 float* __restrict__ dist2) {
    int bid = blockIdx.x;
    if (bid < POOL_BLOCKS) {
        int q = bid * 256 + threadIdx.x;
        if (q >= QUADS) return;
        int tid0 = q * 4;
        int b = tid0 / NT;
        int r0 = tid0 - b * NT;
        const float4* p = (const float4*)(x + (size_t)b * Cn * NT + r0);
        const int cstride = NT / 4;   // 975 float4s between channels

        float4 s1 = make_float4(0.f, 0.f, 0.f, 0.f);
        float4 s2 = make_float4(0.f, 0.f, 0.f, 0.f);
#pragma unroll
        for (int c = 0; c < 32; ++c) {
            float4 v = p[c * cstride];
            s1.x += v.x; s1.y += v.y; s1.z += v.z; s1.w += v.w;
        }
#pragma unroll
        for (int c = 32; c < 64; ++c) {
            float4 v = p[c * cstride];
            s2.x += v.x; s2.y += v.y; s2.z += v.z; s2.w += v.w;
        }

        float l1 = sp(l1p[0]);
        float l2 = sp(l2p[0]);
        float a1[4] = {s1.x, s1.y, s1.z, s1.w};
        float a2[4] = {s2.x, s2.y, s2.z, s2.w};
#pragma unroll
        for (int m = 0; m < 4; ++m) {
            int r = r0 + m;
            int n = r / Tn;
            int t = r - n * Tn;
            int o = (b * Tn + t) * Nn + n;   // [bt, n] layout
            float v1 = sp(a1[m] * (1.0f / 32.0f)) + 1.0f;
            float v2 = sp(a2[m] * (1.0f / 32.0f)) + 1.0f;
            x1p[o] = powf(v1, l1);
            x2p[o] = powf(v2, l2);
        }
    } else {
        int tid = (bid - POOL_BLOCKS) * 256 + threadIdx.x;
        if (tid >= Nn * Nn) return;
        float e = 2.0f * sp(l3p[0]);
        dist2[tid] = powf(dist[tid], e);
    }
}

// One wave (64 lanes) per output row; 325 elements -> 6 regs/lane.
// a_ij = (g * (x1p_i * x2p_j)) * dist2_ij  (association matches reference)
__global__ __launch_bounds__(256)
void softmax_kernel(const float* __restrict__ x1p,
                    const float* __restrict__ x2p,
                    const float* __restrict__ dist2,
                    const float* __restrict__ Gp,
                    float* __restrict__ out) {
    int wid  = blockIdx.x * (blockDim.x >> 6) + (threadIdx.x >> 6);
    int lane = threadIdx.x & 63;
    if (wid >= ROWS) return;

    int bt = wid / Nn;
    int i  = wid - bt * Nn;

    float g   = sp(Gp[0]);
    float x1v = x1p[wid];                 // wid == bt*Nn + i
    const float* x2row = x2p + bt * Nn;   // L2-resident (1 MB total)
    const float* drow  = dist2 + i * Nn;  // L2-resident (0.4 MB total)

    float a[6];
    float m = -INFINITY;
#pragma unroll
    for (int k = 0; k < 6; ++k) {
        int j = lane + 64 * k;
        float av = -INFINITY;
        if (j < Nn) av = (g * (x1v * x2row[j])) * drow[j];
        a[k] = av;
        m = fmaxf(m, av);
    }
#pragma unroll
    for (int off = 32; off; off >>= 1) m = fmaxf(m, __shfl_xor(m, off, 64));

    float s = 0.0f;
#pragma unroll
    for (int k = 0; k < 6; ++k) {
        int j = lane + 64 * k;
        float e = 0.0f;
        if (j < Nn) e = expf(a[k] - m);
        a[k] = e;
        s += e;
    }
#pragma unroll
    for (int off = 32; off; off >>= 1) s += __shfl_xor(s, off, 64);

    float inv = 1.0f / s;
    float* orow = out + (size_t)wid * Nn;
#pragma unroll
    for (int k = 0; k < 6; ++k) {
        int j = lane + 64 * k;
        if (j < Nn) __builtin_nontemporal_store(a[k] * inv, orow + j);
    }
}

extern "C" void kernel_launch(void* const* d_in, const int* in_sizes, int n_in,
                              void* d_out, int out_size, void* d_ws, size_t ws_size,
                              hipStream_t stream) {
    const float* x    = (const float*)d_in[0];
    const float* dist = (const float*)d_in[1];
    const float* l1   = (const float*)d_in[2];
    const float* l2   = (const float*)d_in[3];
    const float* l3   = (const float*)d_in[4];
    const float* G    = (const float*)d_in[5];
    float* out = (float*)d_out;

    float* ws    = (float*)d_ws;
    float* x1p   = ws;                 // ROWS floats
    float* x2p   = ws + ROWS;          // ROWS floats
    float* dist2 = ws + 2 * ROWS;      // Nn*Nn floats (total ~2.4 MB)

    prep_kernel<<<POOL_BLOCKS + DIST_BLOCKS, 256, 0, stream>>>(
        x, dist, l1, l2, l3, x1p, x2p, dist2);
    softmax_kernel<<<ROWS / 4, 256, 0, stream>>>(x1p, x2p, dist2, G, out);
}